// Round 2
// baseline (492.269 us; speedup 1.0000x reference)
//
#include <hip/hip_runtime.h>

typedef int int32x4 __attribute__((ext_vector_type(4)));

// ---------------------------------------------------------------------------
// maxabs reduction (for weight_scale = max|W| / 7)
// ---------------------------------------------------------------------------
__global__ void maxabs_kernel(const float* __restrict__ x, int n4,
                              unsigned* __restrict__ out) {
    float m = 0.f;
    int i = blockIdx.x * blockDim.x + threadIdx.x;
    int stride = gridDim.x * blockDim.x;
    const float4* x4 = (const float4*)x;
    for (int j = i; j < n4; j += stride) {
        float4 v = x4[j];
        m = fmaxf(m, fmaxf(fmaxf(fabsf(v.x), fabsf(v.y)),
                           fmaxf(fabsf(v.z), fabsf(v.w))));
    }
#pragma unroll
    for (int off = 32; off; off >>= 1)
        m = fmaxf(m, __shfl_down(m, off, 64));
    __shared__ float wm[4];
    int ln = threadIdx.x & 63, wv = threadIdx.x >> 6;
    if (ln == 0) wm[wv] = m;
    __syncthreads();
    if (threadIdx.x == 0) {
        float bm = fmaxf(fmaxf(wm[0], wm[1]), fmaxf(wm[2], wm[3]));
        atomicMax(out, __float_as_uint(bm));  // nonneg floats: bit order ok
    }
}

// ---------------------------------------------------------------------------
// fake-quant to int8 codes: clip(round(x / s), lo, hi), packed 4/thread
// ---------------------------------------------------------------------------
__global__ void quant_kernel(const float* __restrict__ x, int n4,
                             const float* __restrict__ sptr, float sdiv,
                             float lo, float hi, char* __restrict__ out) {
    float s = sptr[0] / sdiv;
    int i = blockIdx.x * blockDim.x + threadIdx.x;
    int stride = gridDim.x * blockDim.x;
    const float4* x4 = (const float4*)x;
    int* o4 = (int*)out;
    for (int j = i; j < n4; j += stride) {
        float4 v = x4[j];
        int a = (int)fminf(fmaxf(rintf(v.x / s), lo), hi);
        int b = (int)fminf(fmaxf(rintf(v.y / s), lo), hi);
        int c = (int)fminf(fmaxf(rintf(v.z / s), lo), hi);
        int d = (int)fminf(fmaxf(rintf(v.w / s), lo), hi);
        o4[j] = (a & 255) | ((b & 255) << 8) | ((c & 255) << 16) | ((d & 255) << 24);
    }
}

// ---------------------------------------------------------------------------
// int8 GEMM, C[m,n] = sum_k A[m,k]*B[n,k]  (both row-major [.,K])
// 128x128 tile, BK=64 bytes, 4-deep LDS ring (4 x 16 KiB), counted vmcnt:
// iteration t stages tile t+3 (slot free since end of iter t-1), then waits
// vmcnt(12) so 3 tiles stay in flight across barriers (T3+T4). Raw s_barrier
// + sched_barrier fences; s_setprio around the 16-MFMA cluster (T5).
// LDS swizzle: 16B chunk ^= (row>>1)&3 -> consecutive 8 lanes hit all 8
// bank groups on ds_read_b128; source address pre-swizzled (rule #21).
// ---------------------------------------------------------------------------
#define GEMM_STEP(T_, VMC_, DO_STAGE_)                                        \
  {                                                                           \
    const int t_ = (T_);                                                      \
    if (DO_STAGE_) stage(t_ + 3);                                             \
    asm volatile("s_waitcnt vmcnt(" VMC_ ")" ::: "memory");                   \
    __builtin_amdgcn_s_barrier();                                             \
    __builtin_amdgcn_sched_barrier(0);                                        \
    const char* la_ = lA[t_ & 3];                                             \
    const char* lb_ = lB[t_ & 3];                                             \
    int32x4 af[4], bf[4];                                                     \
    _Pragma("unroll")                                                         \
    for (int mf = 0; mf < 4; ++mf) {                                          \
      int row = wr * 64 + mf * 16 + lnlo;                                     \
      int c = lnhi ^ ((row >> 1) & 3);                                        \
      af[mf] = *(const int32x4*)(la_ + row * 64 + c * 16);                    \
    }                                                                         \
    _Pragma("unroll")                                                         \
    for (int nf = 0; nf < 4; ++nf) {                                          \
      int col = wc * 64 + nf * 16 + lnlo;                                     \
      int c = lnhi ^ ((col >> 1) & 3);                                        \
      bf[nf] = *(const int32x4*)(lb_ + col * 64 + c * 16);                    \
    }                                                                         \
    asm volatile("s_waitcnt lgkmcnt(0)" ::: "memory");                        \
    __builtin_amdgcn_s_barrier();                                             \
    __builtin_amdgcn_sched_barrier(0);                                        \
    __builtin_amdgcn_s_setprio(1);                                            \
    _Pragma("unroll")                                                         \
    for (int mf = 0; mf < 4; ++mf)                                            \
      _Pragma("unroll")                                                       \
      for (int nf = 0; nf < 4; ++nf)                                          \
        acc[mf][nf] = __builtin_amdgcn_mfma_i32_16x16x64_i8(                  \
            af[mf], bf[nf], acc[mf][nf], 0, 0, 0);                            \
    __builtin_amdgcn_s_setprio(0);                                            \
  }

template <bool FIRST>
__global__ __launch_bounds__(256, 2)
void gemm_i8_kernel(const char* __restrict__ A, const char* __restrict__ B,
                    int M, int N, int K,
                    const float* __restrict__ sa_ptr,
                    const float* __restrict__ wmax_ptr,
                    const float* __restrict__ bias,
                    const float* __restrict__ s2_ptr,
                    char* __restrict__ out8, float* __restrict__ outf) {
    __shared__ __align__(16) char lA[4][128 * 64];  // 4-slot ring, 32 KiB
    __shared__ __align__(16) char lB[4][128 * 64];  // 32 KiB

    const int tid = threadIdx.x;
    const int wv = tid >> 6, ln = tid & 63;
    const int lnlo = ln & 15, lnhi = ln >> 4;
    const int m0 = blockIdx.y * 128;
    const int n0 = blockIdx.x * 128;
    const int wr = wv >> 1, wc = wv & 1;

    int32x4 acc[4][4] = {};

    const int nkt = K >> 6;  // BK = 64

    // stage tile t into slot t&3: 4 loads/thread (2 A + 2 B), 16B each,
    // wave-uniform LDS base + lane*16 (global_load_lds contract),
    // global source pre-swizzled so LDS stays linear.
    auto stage = [&](int t) {
        const int slot = t & 3;
        const long k0 = (long)t << 6;
#pragma unroll
        for (int r = 0; r < 2; ++r) {
            int s = r * 256 + tid;            // 16B slot 0..511
            int row = s >> 2;                 // 4 chunks per 64B row
            int cs = s & 3;
            int c = cs ^ ((row >> 1) & 3);    // inverse swizzle on source
            long ga = (long)(m0 + row) * K + k0 + c * 16;
            long gb = (long)(n0 + row) * K + k0 + c * 16;
            int lbase = (r * 256 + wv * 64) * 16;
            __builtin_amdgcn_global_load_lds(
                (const __attribute__((address_space(1))) void*)(A + ga),
                (__attribute__((address_space(3))) void*)(lA[slot] + lbase), 16, 0, 0);
            __builtin_amdgcn_global_load_lds(
                (const __attribute__((address_space(1))) void*)(B + gb),
                (__attribute__((address_space(3))) void*)(lB[slot] + lbase), 16, 0, 0);
        }
    };

    // prologue: 3 tiles in flight
    stage(0);
    stage(1);
    stage(2);

    int t = 0;
    const int nmain = nkt - 3;
    for (; t < nmain; ++t) {
        GEMM_STEP(t, "12", true);   // stage t+3; 3 tiles stay in flight
    }
    GEMM_STEP(t, "8", false); ++t;  // drain: 2 tiles in flight
    GEMM_STEP(t, "4", false); ++t;  // 1 tile in flight
    GEMM_STEP(t, "0", false);       // last tile

    // ---- epilogue (layout identical to verified round-1 kernel) ----
    float sa = sa_ptr[0];
    float sw = wmax_ptr[0] / 7.0f;
    float sab = sa * sw;
    float s2 = FIRST ? s2_ptr[0] : 0.f;

#pragma unroll
    for (int nf = 0; nf < 4; ++nf) {
        int col = n0 + wc * 64 + nf * 16 + lnlo;
        float bq = rintf(bias[col] / sab) * sab;  // Int32Bias fake-quant
#pragma unroll
        for (int mf = 0; mf < 4; ++mf) {
            int rbase = m0 + wr * 64 + mf * 16 + (lnhi << 2);
#pragma unroll
            for (int i = 0; i < 4; ++i) {
                float h = sab * (float)acc[mf][nf][i] + bq;
                long off = (long)(rbase + i) * N + col;
                if constexpr (FIRST) {
                    h = fmaxf(h, 0.f);
                    float q = fminf(fmaxf(rintf(h / s2), 0.f), 15.f);
                    out8[off] = (char)(int)q;
                } else {
                    outf[off] = h;
                }
            }
        }
    }
}

// ---------------------------------------------------------------------------
// launch
// ---------------------------------------------------------------------------
extern "C" void kernel_launch(void* const* d_in, const int* in_sizes, int n_in,
                              void* d_out, int out_size, void* d_ws, size_t ws_size,
                              hipStream_t stream) {
    const float* x  = (const float*)d_in[0];   // [4,2048,2048] -> [8192,2048]
    const float* W1 = (const float*)d_in[1];   // [8192,2048]
    const float* b1 = (const float*)d_in[2];   // [8192]
    const float* W2 = (const float*)d_in[3];   // [2048,8192]
    const float* b2 = (const float*)d_in[4];   // [2048]
    const float* s1 = (const float*)d_in[5];
    const float* s2 = (const float*)d_in[6];

    const int M = 8192, D = 2048, F = 8192;

    char* ws = (char*)d_ws;
    unsigned* mx1 = (unsigned*)ws;        // maxabs(W1) as float bits
    unsigned* mx2 = (unsigned*)(ws + 4);  // maxabs(W2)
    char* xq  = ws + 256;                  // [M,D]  int8
    char* w1q = xq + (size_t)M * D;        // [F,D]  int8
    char* w2q = w1q + (size_t)F * D;       // [D,F]  int8
    char* hq  = w2q + (size_t)D * F;       // [M,F]  int8 (h_q codes 0..15)

    hipMemsetAsync(d_ws, 0, 8, stream);   // zero the maxabs slots

    maxabs_kernel<<<2048, 256, 0, stream>>>(W1, (F * D) >> 2, mx1);
    maxabs_kernel<<<2048, 256, 0, stream>>>(W2, (D * F) >> 2, mx2);

    quant_kernel<<<2048, 256, 0, stream>>>(x,  (M * D) >> 2, s1, 1.f, -8.f, 7.f, xq);
    quant_kernel<<<2048, 256, 0, stream>>>(W1, (F * D) >> 2, (const float*)mx1, 7.f, -8.f, 7.f, w1q);
    quant_kernel<<<2048, 256, 0, stream>>>(W2, (D * F) >> 2, (const float*)mx2, 7.f, -8.f, 7.f, w2q);

    gemm_i8_kernel<true><<<dim3(F / 128, M / 128), 256, 0, stream>>>(
        xq, w1q, M, F, D, s1, (const float*)mx1, b1, s2, hq, nullptr);

    gemm_i8_kernel<false><<<dim3(D / 128, M / 128), 256, 0, stream>>>(
        hq, w2q, M, D, F, s2, (const float*)mx2, b2, nullptr, nullptr, (float*)d_out);
}

// Round 3
// 455.470 us; speedup vs baseline: 1.0808x; 1.0808x over previous
//
#include <hip/hip_runtime.h>

typedef int int32x4 __attribute__((ext_vector_type(4)));

// ---------------------------------------------------------------------------
// maxabs reduction (for weight_scale = max|W| / 7)
// ---------------------------------------------------------------------------
__global__ void maxabs_kernel(const float* __restrict__ x, int n4,
                              unsigned* __restrict__ out) {
    float m = 0.f;
    int i = blockIdx.x * blockDim.x + threadIdx.x;
    int stride = gridDim.x * blockDim.x;
    const float4* x4 = (const float4*)x;
    for (int j = i; j < n4; j += stride) {
        float4 v = x4[j];
        m = fmaxf(m, fmaxf(fmaxf(fabsf(v.x), fabsf(v.y)),
                           fmaxf(fabsf(v.z), fabsf(v.w))));
    }
#pragma unroll
    for (int off = 32; off; off >>= 1)
        m = fmaxf(m, __shfl_down(m, off, 64));
    __shared__ float wm[4];
    int ln = threadIdx.x & 63, wv = threadIdx.x >> 6;
    if (ln == 0) wm[wv] = m;
    __syncthreads();
    if (threadIdx.x == 0) {
        float bm = fmaxf(fmaxf(wm[0], wm[1]), fmaxf(wm[2], wm[3]));
        atomicMax(out, __float_as_uint(bm));  // nonneg floats: bit order ok
    }
}

// ---------------------------------------------------------------------------
// fake-quant to int8 codes: clip(round(x / s), lo, hi), packed 4/thread
// ---------------------------------------------------------------------------
__global__ void quant_kernel(const float* __restrict__ x, int n4,
                             const float* __restrict__ sptr, float sdiv,
                             float lo, float hi, char* __restrict__ out) {
    float s = sptr[0] / sdiv;
    int i = blockIdx.x * blockDim.x + threadIdx.x;
    int stride = gridDim.x * blockDim.x;
    const float4* x4 = (const float4*)x;
    int* o4 = (int*)out;
    for (int j = i; j < n4; j += stride) {
        float4 v = x4[j];
        int a = (int)fminf(fmaxf(rintf(v.x / s), lo), hi);
        int b = (int)fminf(fmaxf(rintf(v.y / s), lo), hi);
        int c = (int)fminf(fmaxf(rintf(v.z / s), lo), hi);
        int d = (int)fminf(fmaxf(rintf(v.w / s), lo), hi);
        o4[j] = (a & 255) | ((b & 255) << 8) | ((c & 255) << 16) | ((d & 255) << 24);
    }
}

// ---------------------------------------------------------------------------
// int8 GEMM, C[m,n] = sum_k A[m,k]*B[n,k] (both row-major [.,K]).
// 256x256 tile, BK=128 B, 512 threads (8 waves: 2 wm x 4 wn), 8-phase
// schedule (m201 template ported to i8; fragments are byte-identical to
// bf16 16x16x32). LDS per operand: [2 buf][2 kh][256 rows][64 B] = 64 KiB,
// total 128 KiB -> 1 block/CU. Chunk swizzle c ^= (row>>1)&3 (<=2-way,
// free per m136), source pre-swizzled (rule #21).
// Per K-tile t (buf b=t&1), phases (kh,mh): (0,0)(0,1)(1,0)(1,1); stages:
//   P0: A_kh1(t+1)  P1: B_kh1(t+1)   -> other buffer, never conflicts
//   P2: A_kh0(t+2)  P3: B_kh0(t+2)   -> buf b, kh0 reads drained at P1 end
// Boundary s_waitcnt vmcnt(4): leaves exactly t+2's two kh0 half-slabs in
// flight => tile t+1 fully landed; never drains to 0 mid-loop (T4).
// ---------------------------------------------------------------------------
#define PHASE(B_, KH_, MH_, LOADB_, STG_, VMC_)                                \
  {                                                                            \
    if (LOADB_) {                                                              \
      _Pragma("unroll")                                                        \
      for (int nf = 0; nf < 4; ++nf)                                           \
        bf[nf] = *(const int32x4*)(&lB[B_][KH_][0] +                           \
                                   (wn * 64 + nf * 16) * 64 + coff);           \
    }                                                                          \
    int32x4 af[4];                                                             \
    _Pragma("unroll")                                                          \
    for (int mf = 0; mf < 4; ++mf)                                             \
      af[mf] = *(const int32x4*)(&lA[B_][KH_][0] +                             \
                                 (wm * 128 + MH_ * 64 + mf * 16) * 64 + coff); \
    STG_;                                                                      \
    __builtin_amdgcn_s_barrier();                                              \
    asm volatile("s_waitcnt lgkmcnt(0)" ::: "memory");                         \
    __builtin_amdgcn_sched_barrier(0);                                         \
    __builtin_amdgcn_s_setprio(1);                                             \
    _Pragma("unroll")                                                          \
    for (int mf = 0; mf < 4; ++mf)                                             \
      _Pragma("unroll")                                                        \
      for (int nf = 0; nf < 4; ++nf)                                           \
        acc[MH_ * 4 + mf][nf] = __builtin_amdgcn_mfma_i32_16x16x64_i8(         \
            af[mf], bf[nf], acc[MH_ * 4 + mf][nf], 0, 0, 0);                   \
    __builtin_amdgcn_s_setprio(0);                                             \
    VMC_;                                                                      \
    __builtin_amdgcn_s_barrier();                                              \
  }

template <bool FIRST>
__global__ __launch_bounds__(512, 2)
void gemm_i8_kernel(const char* __restrict__ A, const char* __restrict__ B,
                    int M, int N, int K,
                    const float* __restrict__ sa_ptr,
                    const float* __restrict__ wmax_ptr,
                    const float* __restrict__ bias,
                    const float* __restrict__ s2_ptr,
                    char* __restrict__ out8, float* __restrict__ outf) {
    __shared__ __align__(16) char lA[2][2][256 * 64];  // 64 KiB
    __shared__ __align__(16) char lB[2][2][256 * 64];  // 64 KiB

    const int tid = threadIdx.x;
    const int wv = tid >> 6, ln = tid & 63;
    const int lo = ln & 15, hi = ln >> 4;
    const int wm = wv >> 2, wn = wv & 3;
    const long m0 = (long)blockIdx.y * 256;
    const long n0 = (long)blockIdx.x * 256;

    int32x4 acc[8][4] = {};
    int32x4 bf[4];
    // frag read offset within a [256][64] slab; (row>>1)&3 == (lo>>1)&3
    const int coff = lo * 64 + ((hi ^ ((lo >> 1) & 3)) << 4);

    const int nkt = K >> 7;  // K-tiles of 128 B

    // stage one (operand, tile, kh) 16 KiB half-slab: 2 loads/thread,
    // wave-uniform LDS base + lane*16; global source pre-swizzled.
    auto stg_a = [&](int t, int kh) {
#pragma unroll
        for (int r = 0; r < 2; ++r) {
            int s = r * 512 + tid;
            int row = s >> 2;
            int c = (s & 3) ^ ((row >> 1) & 3);
            long g = (m0 + row) * K + ((long)t << 7) + (kh << 6) + c * 16;
            __builtin_amdgcn_global_load_lds(
                (const __attribute__((address_space(1))) void*)(A + g),
                (__attribute__((address_space(3))) void*)(
                    &lA[t & 1][kh][0] + (r * 512 + wv * 64) * 16), 16, 0, 0);
        }
    };
    auto stg_b = [&](int t, int kh) {
#pragma unroll
        for (int r = 0; r < 2; ++r) {
            int s = r * 512 + tid;
            int row = s >> 2;
            int c = (s & 3) ^ ((row >> 1) & 3);
            long g = (n0 + row) * K + ((long)t << 7) + (kh << 6) + c * 16;
            __builtin_amdgcn_global_load_lds(
                (const __attribute__((address_space(1))) void*)(B + g),
                (__attribute__((address_space(3))) void*)(
                    &lB[t & 1][kh][0] + (r * 512 + wv * 64) * 16), 16, 0, 0);
        }
    };

    // prologue: tile 0 (both kh) + tile 1 kh0; wait so tile 0 is landed
    // (vmcnt(4) leaves only tile1-kh0's 4 loads in flight)
    stg_a(0, 0); stg_b(0, 0); stg_a(0, 1); stg_b(0, 1);
    stg_a(1, 0); stg_b(1, 0);
    asm volatile("s_waitcnt vmcnt(4)" ::: "memory");
    __builtin_amdgcn_s_barrier();

    for (int t = 0; t < nkt - 2; ++t) {
        const int b = t & 1;
        PHASE(b, 0, 0, true,  stg_a(t + 1, 1), );
        PHASE(b, 0, 1, false, stg_b(t + 1, 1), );
        PHASE(b, 1, 0, true,  stg_a(t + 2, 0), );
        PHASE(b, 1, 1, false, stg_b(t + 2, 0),
              asm volatile("s_waitcnt vmcnt(4)" ::: "memory"));
    }
    {   // t = nkt-2: only tile nkt-1 kh1 to stage; drain fully at end
        const int t = nkt - 2, b = t & 1;
        PHASE(b, 0, 0, true,  stg_a(t + 1, 1), );
        PHASE(b, 0, 1, false, stg_b(t + 1, 1), );
        PHASE(b, 1, 0, true,  , );
        PHASE(b, 1, 1, false, ,
              asm volatile("s_waitcnt vmcnt(0)" ::: "memory"));
    }
    {   // t = nkt-1: compute only
        const int b = (nkt - 1) & 1;
        PHASE(b, 0, 0, true,  , );
        PHASE(b, 0, 1, false, , );
        PHASE(b, 1, 0, true,  , );
        PHASE(b, 1, 1, false, , );
    }

    // ---- epilogue (same C/D mapping as verified round-1 kernel) ----
    float sa = sa_ptr[0];
    float sw = wmax_ptr[0] / 7.0f;
    float sab = sa * sw;
    float s2v = FIRST ? s2_ptr[0] : 0.f;

#pragma unroll
    for (int nf = 0; nf < 4; ++nf) {
        long col = n0 + wn * 64 + nf * 16 + lo;
        float bq = rintf(bias[col] / sab) * sab;  // Int32Bias fake-quant
#pragma unroll
        for (int am = 0; am < 8; ++am) {
            long rbase = m0 + wm * 128 + (am >> 2) * 64 + (am & 3) * 16 + (hi << 2);
#pragma unroll
            for (int i = 0; i < 4; ++i) {
                float h = sab * (float)acc[am][nf][i] + bq;
                long off = (rbase + i) * N + col;
                if constexpr (FIRST) {
                    h = fmaxf(h, 0.f);
                    float q = fminf(fmaxf(rintf(h / s2v), 0.f), 15.f);
                    out8[off] = (char)(int)q;
                } else {
                    outf[off] = h;
                }
            }
        }
    }
}

// ---------------------------------------------------------------------------
// launch
// ---------------------------------------------------------------------------
extern "C" void kernel_launch(void* const* d_in, const int* in_sizes, int n_in,
                              void* d_out, int out_size, void* d_ws, size_t ws_size,
                              hipStream_t stream) {
    const float* x  = (const float*)d_in[0];   // [4,2048,2048] -> [8192,2048]
    const float* W1 = (const float*)d_in[1];   // [8192,2048]
    const float* b1 = (const float*)d_in[2];   // [8192]
    const float* W2 = (const float*)d_in[3];   // [2048,8192]
    const float* b2 = (const float*)d_in[4];   // [2048]
    const float* s1 = (const float*)d_in[5];
    const float* s2 = (const float*)d_in[6];

    const int M = 8192, D = 2048, F = 8192;

    char* ws = (char*)d_ws;
    unsigned* mx1 = (unsigned*)ws;        // maxabs(W1) as float bits
    unsigned* mx2 = (unsigned*)(ws + 4);  // maxabs(W2)
    char* xq  = ws + 256;                  // [M,D]  int8
    char* w1q = xq + (size_t)M * D;        // [F,D]  int8
    char* w2q = w1q + (size_t)F * D;       // [D,F]  int8
    char* hq  = w2q + (size_t)D * F;       // [M,F]  int8 (h_q codes 0..15)

    hipMemsetAsync(d_ws, 0, 8, stream);   // zero the maxabs slots

    maxabs_kernel<<<2048, 256, 0, stream>>>(W1, (F * D) >> 2, mx1);
    maxabs_kernel<<<2048, 256, 0, stream>>>(W2, (D * F) >> 2, mx2);

    quant_kernel<<<2048, 256, 0, stream>>>(x,  (M * D) >> 2, s1, 1.f, -8.f, 7.f, xq);
    quant_kernel<<<2048, 256, 0, stream>>>(W1, (F * D) >> 2, (const float*)mx1, 7.f, -8.f, 7.f, w1q);
    quant_kernel<<<2048, 256, 0, stream>>>(W2, (D * F) >> 2, (const float*)mx2, 7.f, -8.f, 7.f, w2q);

    gemm_i8_kernel<true><<<dim3(F / 256, M / 256), 512, 0, stream>>>(
        xq, w1q, M, F, D, s1, (const float*)mx1, b1, s2, hq, nullptr);

    gemm_i8_kernel<false><<<dim3(D / 256, M / 256), 512, 0, stream>>>(
        hq, w2q, M, D, F, s2, (const float*)mx2, b2, nullptr, nullptr, (float*)d_out);
}